// Round 5
// baseline (580.290 us; speedup 1.0000x reference)
//
#include <hip/hip_runtime.h>

// DenseGrid trilinear interpolation, MI355X.
// R7: move the permutation from the write side to the read side.
// R3-R6 invariant: every sorted variant pinned at ~205-230 us with WRITE ~203MB
// of scattered 72-B nt stores (random partial-line HBM writes ~1 TB/s). Fix:
//  - k_fused: one block per fine coarse bin (1024 bins, ~2048 pts). Loads its
//    rec span into LDS, orders by (y,x-chunk) key, gathers codebook (cache-hot)
//    and writes features CONTIGUOUSLY in sorted order to feat_s (coalesced,
//    cacheable -> L3) + inv[p] = sorted_pos. Subsort kernel eliminated.
//  - k_unsort: original order; s = inv[p] coalesced; random 72-B READ from
//    L3-resident feat_s; COALESCED nt write to out[p]. Write side back to
//    compulsory 151 MB at stream rate; reads have no RMW penalty.
// Identical per-point fma chain everywhere -> absmax unchanged.
// Fallbacks: no feat_s room -> sorted direct-scatter (R6-like); tiny ws -> R2.

constexpr int RES  = 128;
constexpr int NBA  = 1024;          // coarse bins: (iz0<<3)|(iy0>>4)
constexpr int TPM  = 576;           // 9 threads/point, 64 pts/chunk
constexpr int PPB  = 64;
constexpr int SUB_CAP = 3264;       // recs cached in LDS per bin (mean 2048, +27sigma)

constexpr int HIST_CHUNK = 1024;
constexpr int SCAT_CHUNK = 4096;

typedef float vf2 __attribute__((ext_vector_type(2)));
typedef float vf4 __attribute__((ext_vector_type(4)));

struct Xf {
    float m00, m01, m02, m10, m11, m12, m20, m21, m22;
    float tx, ty, tz;
};

__device__ __forceinline__ Xf load_xf(const float* __restrict__ tr) {
    Xf X;
    const float a = tr[0], b = tr[1],  c = tr[2];
    const float d = tr[4], e = tr[5],  g = tr[6];
    const float h = tr[8], i = tr[9],  j = tr[10];
    X.tx = tr[3]; X.ty = tr[7]; X.tz = tr[11];
    const float det = a*(e*j - g*i) - b*(d*j - g*h) + c*(d*i - e*h);
    const float rd  = 1.0f / det;
    X.m00 = (e*j - g*i) * rd; X.m01 = (c*i - b*j) * rd; X.m02 = (b*g - c*e) * rd;
    X.m10 = (g*h - d*j) * rd; X.m11 = (a*j - c*h) * rd; X.m12 = (c*d - a*g) * rd;
    X.m20 = (d*i - e*h) * rd; X.m21 = (b*h - a*i) * rd; X.m22 = (a*e - b*d) * rd;
    return X;
}

// Explicit fma chain: identical across all kernels (bin assignment must match).
__device__ __forceinline__ float qcoord(float m0, float m1, float m2,
                                        float x, float y, float z) {
    return __fmaf_rn(m0, x, __fmaf_rn(m1, y, m2 * z)) * (float)(RES - 1);
}

__device__ __forceinline__ int clamp_idx(float q) {
    return min(max((int)floorf(q), 0), RES - 1);
}

__device__ __forceinline__ int coarse_key(float qy, float qz) {
    return (clamp_idx(qz) << 3) | (clamp_idx(qy) >> 4);
}

// ---------------------------------------------------------------- pass A ----
__global__ __launch_bounds__(256)
void k_histA(const float* __restrict__ pts, const float* __restrict__ tr,
             unsigned* __restrict__ histA, int npts)
{
    __shared__ unsigned sh[NBA];
    const int t = threadIdx.x;
    for (int b = t; b < NBA; b += 256) sh[b] = 0u;
    __syncthreads();
    const Xf X = load_xf(tr);
    const int base = blockIdx.x * HIST_CHUNK;
    #pragma unroll
    for (int i = 0; i < HIST_CHUNK / 256; ++i) {
        const int p = base + t + i * 256;
        if (p < npts) {
            const float x = pts[p*3 + 0] - X.tx;
            const float y = pts[p*3 + 1] - X.ty;
            const float z = pts[p*3 + 2] - X.tz;
            const float qy = qcoord(X.m10, X.m11, X.m12, x, y, z);
            const float qz = qcoord(X.m20, X.m21, X.m22, x, y, z);
            atomicAdd(&sh[coarse_key(qy, qz)], 1u);
        }
    }
    __syncthreads();
    for (int b = t; b < NBA; b += 256) {
        const unsigned c = sh[b];
        if (c) atomicAdd(&histA[b], c);
    }
}

__global__ __launch_bounds__(NBA)
void k_scanA(const unsigned* __restrict__ histA,
             unsigned* __restrict__ baseA, unsigned* __restrict__ cursorA)
{
    __shared__ unsigned s[NBA];
    const int t = threadIdx.x;
    const unsigned my = histA[t];
    s[t] = my;
    __syncthreads();
    for (int off = 1; off < NBA; off <<= 1) {
        const unsigned v = (t >= off) ? s[t - off] : 0u;
        __syncthreads();
        s[t] += v;
        __syncthreads();
    }
    baseA[t]   = s[t] - my;
    cursorA[t] = s[t] - my;
}

__global__ __launch_bounds__(256)
void k_scatA(const float* __restrict__ pts, const float* __restrict__ tr,
             unsigned* __restrict__ cursorA, vf4* __restrict__ rec, int npts)
{
    __shared__ unsigned shist[NBA], sbase[NBA], scur[NBA];
    const int t = threadIdx.x;
    for (int b = t; b < NBA; b += 256) { shist[b] = 0u; scur[b] = 0u; }
    __syncthreads();
    const Xf X = load_xf(tr);
    const int base = blockIdx.x * SCAT_CHUNK;
    #pragma unroll
    for (int i = 0; i < SCAT_CHUNK / 256; ++i) {
        const int p = base + t + i * 256;
        if (p < npts) {
            const float x = pts[p*3 + 0] - X.tx;
            const float y = pts[p*3 + 1] - X.ty;
            const float z = pts[p*3 + 2] - X.tz;
            const float qy = qcoord(X.m10, X.m11, X.m12, x, y, z);
            const float qz = qcoord(X.m20, X.m21, X.m22, x, y, z);
            atomicAdd(&shist[coarse_key(qy, qz)], 1u);
        }
    }
    __syncthreads();
    for (int b = t; b < NBA; b += 256)
        sbase[b] = shist[b] ? atomicAdd(&cursorA[b], shist[b]) : 0u;
    __syncthreads();
    #pragma unroll
    for (int i = 0; i < SCAT_CHUNK / 256; ++i) {
        const int p = base + t + i * 256;
        if (p < npts) {
            const float x = pts[p*3 + 0] - X.tx;
            const float y = pts[p*3 + 1] - X.ty;
            const float z = pts[p*3 + 2] - X.tz;
            const float qx = qcoord(X.m00, X.m01, X.m02, x, y, z);
            const float qy = qcoord(X.m10, X.m11, X.m12, x, y, z);
            const float qz = qcoord(X.m20, X.m21, X.m22, x, y, z);
            const int bn = coarse_key(qy, qz);
            const unsigned r = atomicAdd(&scur[bn], 1u);
            unsigned pos = sbase[bn] + r;
            if (pos >= (unsigned)npts) pos = (unsigned)npts - 1u;  // insurance
            vf4 v; v.x = qx; v.y = qy; v.z = qz; v.w = __int_as_float(p);
            rec[pos] = v;
        }
    }
}

// --------------------------------------------------------------- k_fused ----
// One block per coarse bin: LDS-cache the bin's recs, order by (y-in-16,x>>4),
// gather from cache-hot codebook, write features contiguously in sorted order.
__global__ __launch_bounds__(TPM)
void k_fused(const vf4* __restrict__ rec, const unsigned* __restrict__ histA,
             const unsigned* __restrict__ baseA, const float* __restrict__ cb,
             float* __restrict__ feat_s, unsigned* __restrict__ inv,
             float* __restrict__ out, int direct)
{
    // Bijective XCD swizzle (NBA = 1024 divisible by 8): each XCD walks a
    // contiguous range of bins -> contiguous codebook window in its L2.
    const int bid = blockIdx.x;
    const int bin = (bid & 7) * (NBA / 8) + (bid >> 3);

    const unsigned n  = histA[bin];
    if (n == 0u) return;
    const unsigned b0 = baseA[bin];
    const int ybase = (bin & 7) << 4;

    const int t  = threadIdx.x;
    const int pl = t / 9;
    const int f  = t - pl * 9;

    __shared__ vf4 recs[SUB_CAP];              // 52224 B
    __shared__ unsigned short ord[SUB_CAP];    //  6528 B
    __shared__ unsigned h[128], cur[128];      //  1024 B

    auto emit = [&](const vf4 r, unsigned spos) {
        const float qx = r.x, qy = r.y, qz = r.z;
        const int idx = __float_as_int(r.w);
        const float fx = floorf(qx), fy = floorf(qy), fz = floorf(qz);
        const float wx1 = qx - fx, wy1 = qy - fy, wz1 = qz - fz;
        const float wx0 = 1.0f - wx1, wy0 = 1.0f - wy1, wz0 = 1.0f - wz1;
        const int ix0 = clamp_idx(qx), ix1 = min(ix0 + 1, RES - 1);
        const int iy0 = clamp_idx(qy), iy1 = min(iy0 + 1, RES - 1);
        const int iz0 = clamp_idx(qz), iz1 = min(iz0 + 1, RES - 1);
        vf2 v[8]; float w[8];
        #pragma unroll
        for (int k = 0; k < 8; ++k) {
            const int dx = k & 1, dy = (k >> 1) & 1, dz = k >> 2;
            const int ro = (dx ? ix1 : ix0) + ((dy ? iy1 : iy0) << 7)
                         + ((dz ? iz1 : iz0) << 14);
            v[k] = *reinterpret_cast<const vf2*>(cb + (size_t)ro * 18 + 2 * f);
            w[k] = (dx ? wx1 : wx0) * (dy ? wy1 : wy0) * (dz ? wz1 : wz0);
        }
        float ax = 0.0f, ay = 0.0f;
        #pragma unroll
        for (int k = 0; k < 8; ++k) { ax += v[k].x * w[k]; ay += v[k].y * w[k]; }
        vf2 o; o.x = ax; o.y = ay;
        if (direct) {
            __builtin_nontemporal_store(o,
                reinterpret_cast<vf2*>(out + (size_t)idx * 18 + 2 * f));
        } else {
            *reinterpret_cast<vf2*>(feat_s + (size_t)spos * 18 + 2 * f) = o;
            if (f == 0) inv[idx] = spos;
        }
    };

    if (n > (unsigned)SUB_CAP) {
        // ~27 sigma out, never expected: process in stored (coarse) order.
        for (unsigned off = 0; off < n; off += PPB) {
            const unsigned i = off + (unsigned)pl;
            if (i < n) emit(__builtin_nontemporal_load(&rec[b0 + i]), b0 + i);
        }
        return;
    }

    // Load recs + LDS histogram of fine key (y-in-16, x>>4) -> 128 keys.
    for (int k = t; k < 128; k += TPM) h[k] = 0u;
    __syncthreads();
    for (unsigned i = t; i < n; i += TPM) {
        const vf4 v = __builtin_nontemporal_load(&rec[b0 + i]);
        recs[i] = v;
        const int ky = min(max(clamp_idx(v.y) - ybase, 0), 15);
        const int kx = clamp_idx(v.x) >> 4;
        atomicAdd(&h[(ky << 3) | kx], 1u);
    }
    __syncthreads();
    if (t == 0) {
        unsigned run = 0u;
        for (int k = 0; k < 128; ++k) { cur[k] = run; run += h[k]; }
    }
    __syncthreads();
    for (unsigned i = t; i < n; i += TPM) {
        const vf4 v = recs[i];
        const int ky = min(max(clamp_idx(v.y) - ybase, 0), 15);
        const int kx = clamp_idx(v.x) >> 4;
        ord[atomicAdd(&cur[(ky << 3) | kx], 1u)] = (unsigned short)i;
    }
    __syncthreads();

    for (unsigned off = 0; off < n; off += PPB) {
        const unsigned i = off + (unsigned)pl;
        if (i < n) emit(recs[ord[i]], b0 + i);
    }
}

// -------------------------------------------------------------- k_unsort ----
// Original order: coalesced inv read, random 72-B read from L3-resident
// feat_s, coalesced nt write to out.
__global__ __launch_bounds__(TPM)
void k_unsort(const float* __restrict__ feat_s, const unsigned* __restrict__ inv,
              float* __restrict__ out, int npts)
{
    __shared__ unsigned sinv[PPB];
    const int t = threadIdx.x;
    const int g0 = blockIdx.x * PPB;
    if (t < PPB && g0 + t < npts)
        sinv[t] = __builtin_nontemporal_load(&inv[g0 + t]);
    __syncthreads();

    const int pl = t / 9;
    const int f  = t - pl * 9;
    const int p  = g0 + pl;
    if (p >= npts) return;

    const unsigned s = sinv[pl];
    const vf2 v = *reinterpret_cast<const vf2*>(feat_s + (size_t)s * 18 + 2 * f);
    __builtin_nontemporal_store(v,
        reinterpret_cast<vf2*>(out + (size_t)p * 18 + 2 * f));
}

// ---------------- R2 fallback (used only if workspace is too small) ----------
__global__ __launch_bounds__(TPM)
void dense_grid_trilerp(const float* __restrict__ pts,
                        const float* __restrict__ cb,
                        const float* __restrict__ tr,
                        float* __restrict__ out,
                        int npts)
{
    __shared__ float spts[PPB * 3];
    if (threadIdx.x < PPB * 3) {
        int g = blockIdx.x * (PPB * 3) + threadIdx.x;
        spts[threadIdx.x] = (g < npts * 3) ? __builtin_nontemporal_load(&pts[g]) : 0.0f;
    }
    __syncthreads();

    const int pl = threadIdx.x / 9;
    const int f  = threadIdx.x - pl * 9;
    const int p  = blockIdx.x * PPB + pl;
    if (p >= npts) return;

    const Xf X = load_xf(tr);
    const float x = spts[pl*3 + 0] - X.tx;
    const float y = spts[pl*3 + 1] - X.ty;
    const float z = spts[pl*3 + 2] - X.tz;
    const float qx = qcoord(X.m00, X.m01, X.m02, x, y, z);
    const float qy = qcoord(X.m10, X.m11, X.m12, x, y, z);
    const float qz = qcoord(X.m20, X.m21, X.m22, x, y, z);

    const float fx = floorf(qx), fy = floorf(qy), fz = floorf(qz);
    const float wx1 = qx - fx, wy1 = qy - fy, wz1 = qz - fz;
    const float wx0 = 1.0f - wx1, wy0 = 1.0f - wy1, wz0 = 1.0f - wz1;
    const int ix0 = clamp_idx(qx); const int ix1 = min(ix0 + 1, RES - 1);
    const int iy0 = clamp_idx(qy); const int iy1 = min(iy0 + 1, RES - 1);
    const int iz0 = clamp_idx(qz); const int iz1 = min(iz0 + 1, RES - 1);

    int   ro[8];
    float w[8];
    #pragma unroll
    for (int k = 0; k < 8; ++k) {
        const int dx = k & 1, dy = (k >> 1) & 1, dz = k >> 2;
        ro[k] = (dx ? ix1 : ix0) + ((dy ? iy1 : iy0) << 7) + ((dz ? iz1 : iz0) << 14);
        w[k]  = (dx ? wx1 : wx0) * (dy ? wy1 : wy0) * (dz ? wz1 : wz0);
    }

    const float* cbf = cb + 2 * f;
    vf2 v[8];
    #pragma unroll
    for (int k = 0; k < 8; ++k)
        v[k] = *reinterpret_cast<const vf2*>(cbf + (size_t)ro[k] * 18);

    float ax = 0.0f, ay = 0.0f;
    #pragma unroll
    for (int k = 0; k < 8; ++k) { ax += v[k].x * w[k]; ay += v[k].y * w[k]; }

    vf2 o; o.x = ax; o.y = ay;
    __builtin_nontemporal_store(o, reinterpret_cast<vf2*>(out + p * 18 + 2 * f));
}

extern "C" void kernel_launch(void* const* d_in, const int* in_sizes, int n_in,
                              void* d_out, int out_size, void* d_ws, size_t ws_size,
                              hipStream_t stream) {
    const float* pts = (const float*)d_in[0];   // [4*524288, 3] f32
    const float* cb  = (const float*)d_in[1];   // [128^3, 18] f32
    const float* tr  = (const float*)d_in[2];   // [4,4] f32
    float* out = (float*)d_out;                 // [4*524288, 18] f32

    const int npts = in_sizes[0] / 3;

    // ws layout: meta(3*NBA u32 = 12 KB) | rec(npts*16) | inv(npts*4) | feat_s(npts*72)
    const size_t meta      = (size_t)(NBA * 3) * sizeof(unsigned);
    const size_t rec_b     = (size_t)npts * 16;
    const size_t inv_b     = (size_t)npts * 4;
    const size_t feat_b    = (size_t)npts * 72;
    const size_t need_mid  = meta + rec_b;
    const size_t need_full = meta + rec_b + inv_b + feat_b;

    if (d_ws == nullptr || ws_size < need_mid || npts <= 0) {
        const int blocks = (npts + PPB - 1) / PPB;
        dense_grid_trilerp<<<blocks, TPM, 0, stream>>>(pts, cb, tr, out, npts);
        return;
    }

    unsigned* histA   = (unsigned*)d_ws;
    unsigned* baseA   = histA + NBA;
    unsigned* cursorA = baseA + NBA;
    vf4*      rec     = (vf4*)((char*)d_ws + meta);
    unsigned* inv     = (unsigned*)((char*)d_ws + meta + rec_b);
    float*    feat_s  = (float*)((char*)d_ws + meta + rec_b + inv_b);
    const int full    = (ws_size >= need_full) ? 1 : 0;

    hipMemsetAsync(histA, 0, meta, stream);    // zeroes hist (baseA/cursorA rewritten)
    k_histA<<<(npts + HIST_CHUNK - 1) / HIST_CHUNK, 256, 0, stream>>>(pts, tr, histA, npts);
    k_scanA<<<1, NBA, 0, stream>>>(histA, baseA, cursorA);
    k_scatA<<<(npts + SCAT_CHUNK - 1) / SCAT_CHUNK, 256, 0, stream>>>(pts, tr, cursorA, rec, npts);
    k_fused<<<NBA, TPM, 0, stream>>>(rec, histA, baseA, cb, feat_s, inv, out, full ? 0 : 1);
    if (full)
        k_unsort<<<(npts + PPB - 1) / PPB, TPM, 0, stream>>>(feat_s, inv, out, npts);
}

// Round 6
// 516.801 us; speedup vs baseline: 1.1228x; 1.1228x over previous
//
#include <hip/hip_runtime.h>

// DenseGrid trilinear interpolation, MI355X.
// R8: R6 structure with ONE substantive change: the scattered out-store is
// CACHEABLE (plain store), not nontemporal.
// Evidence: R3-R7 all pinned at ~205 us in the main kernel with WRITE ~204 MB
// of nt 72-B stores to out[original_idx]. NT bypasses L2/L3 -> every store is
// a partial-line RMW at HBM (~1 TB/s). After the fine sort, the codebook's
// live window in L3 is tiny, so out's 151 MB of dirty lines can accumulate in
// the 256-MB L3, merge both point-halves per 128-B line, and write back full
// lines asynchronously. NT-on-scatter was only correct in R2 (it protected
// the randomly re-read codebook); post-sort it is pure overhead.
//  - Pass A: coarse 512-bin block-aggregated counting sort.
//  - Pass B: per-coarse-bin in-LDS in-place subsort, key=(y-in-32, x>>4).
//  - k_main6: 576-thread blocks, 9 threads/point, cache-hot vf2 gathers,
//    cacheable scattered store, bijective XCD swizzle.
// Identical per-point fma chain everywhere -> absmax unchanged.
// Fallback to the R2 single-kernel path if workspace is too small.

constexpr int RES  = 128;
constexpr int NBA  = 512;           // coarse bins: (iz0<<2)|(iy0>>5)
constexpr int TPM  = 576;           // 9 threads/point, 64 pts/block
constexpr int PPB  = 64;
constexpr int SUB_CAP = 8160;       // LDS rec cache per coarse bin (mean 4096)

constexpr int HIST_CHUNK = 1024;
constexpr int SCAT_CHUNK = 8192;    // 256 blocks -> full CU coverage

typedef float vf2 __attribute__((ext_vector_type(2)));
typedef float vf4 __attribute__((ext_vector_type(4)));

struct Xf {
    float m00, m01, m02, m10, m11, m12, m20, m21, m22;
    float tx, ty, tz;
};

__device__ __forceinline__ Xf load_xf(const float* __restrict__ tr) {
    Xf X;
    const float a = tr[0], b = tr[1],  c = tr[2];
    const float d = tr[4], e = tr[5],  g = tr[6];
    const float h = tr[8], i = tr[9],  j = tr[10];
    X.tx = tr[3]; X.ty = tr[7]; X.tz = tr[11];
    const float det = a*(e*j - g*i) - b*(d*j - g*h) + c*(d*i - e*h);
    const float rd  = 1.0f / det;
    X.m00 = (e*j - g*i) * rd; X.m01 = (c*i - b*j) * rd; X.m02 = (b*g - c*e) * rd;
    X.m10 = (g*h - d*j) * rd; X.m11 = (a*j - c*h) * rd; X.m12 = (c*d - a*g) * rd;
    X.m20 = (d*i - e*h) * rd; X.m21 = (b*h - a*i) * rd; X.m22 = (a*e - b*d) * rd;
    return X;
}

// Explicit fma chain: identical across all kernels (bin assignment must match).
__device__ __forceinline__ float qcoord(float m0, float m1, float m2,
                                        float x, float y, float z) {
    return __fmaf_rn(m0, x, __fmaf_rn(m1, y, m2 * z)) * (float)(RES - 1);
}

__device__ __forceinline__ int clamp_idx(float q) {
    return min(max((int)floorf(q), 0), RES - 1);
}

__device__ __forceinline__ int coarse_key(float qy, float qz) {
    return (clamp_idx(qz) << 2) | (clamp_idx(qy) >> 5);
}

// ---------------------------------------------------------------- pass A ----
__global__ __launch_bounds__(256)
void k_histA(const float* __restrict__ pts, const float* __restrict__ tr,
             unsigned* __restrict__ histA, int npts)
{
    __shared__ unsigned sh[NBA];
    const int t = threadIdx.x;
    for (int b = t; b < NBA; b += 256) sh[b] = 0u;
    __syncthreads();
    const Xf X = load_xf(tr);
    const int base = blockIdx.x * HIST_CHUNK;
    #pragma unroll
    for (int i = 0; i < HIST_CHUNK / 256; ++i) {
        const int p = base + t + i * 256;
        if (p < npts) {
            const float x = pts[p*3 + 0] - X.tx;
            const float y = pts[p*3 + 1] - X.ty;
            const float z = pts[p*3 + 2] - X.tz;
            const float qy = qcoord(X.m10, X.m11, X.m12, x, y, z);
            const float qz = qcoord(X.m20, X.m21, X.m22, x, y, z);
            atomicAdd(&sh[coarse_key(qy, qz)], 1u);
        }
    }
    __syncthreads();
    for (int b = t; b < NBA; b += 256) {
        const unsigned c = sh[b];
        if (c) atomicAdd(&histA[b], c);
    }
}

__global__ __launch_bounds__(NBA)
void k_scanA(const unsigned* __restrict__ histA,
             unsigned* __restrict__ baseA, unsigned* __restrict__ cursorA)
{
    __shared__ unsigned s[NBA];
    const int t = threadIdx.x;
    const unsigned my = histA[t];
    s[t] = my;
    __syncthreads();
    for (int off = 1; off < NBA; off <<= 1) {
        const unsigned v = (t >= off) ? s[t - off] : 0u;
        __syncthreads();
        s[t] += v;
        __syncthreads();
    }
    baseA[t]   = s[t] - my;
    cursorA[t] = s[t] - my;
}

__global__ __launch_bounds__(256)
void k_scatA(const float* __restrict__ pts, const float* __restrict__ tr,
             unsigned* __restrict__ cursorA, vf4* __restrict__ rec, int npts)
{
    __shared__ unsigned shist[NBA], sbase[NBA], scur[NBA];
    const int t = threadIdx.x;
    for (int b = t; b < NBA; b += 256) { shist[b] = 0u; scur[b] = 0u; }
    __syncthreads();
    const Xf X = load_xf(tr);
    const int base = blockIdx.x * SCAT_CHUNK;
    #pragma unroll
    for (int i = 0; i < SCAT_CHUNK / 256; ++i) {
        const int p = base + t + i * 256;
        if (p < npts) {
            const float x = pts[p*3 + 0] - X.tx;
            const float y = pts[p*3 + 1] - X.ty;
            const float z = pts[p*3 + 2] - X.tz;
            const float qy = qcoord(X.m10, X.m11, X.m12, x, y, z);
            const float qz = qcoord(X.m20, X.m21, X.m22, x, y, z);
            atomicAdd(&shist[coarse_key(qy, qz)], 1u);
        }
    }
    __syncthreads();
    for (int b = t; b < NBA; b += 256)
        sbase[b] = shist[b] ? atomicAdd(&cursorA[b], shist[b]) : 0u;
    __syncthreads();
    #pragma unroll
    for (int i = 0; i < SCAT_CHUNK / 256; ++i) {
        const int p = base + t + i * 256;
        if (p < npts) {
            const float x = pts[p*3 + 0] - X.tx;
            const float y = pts[p*3 + 1] - X.ty;
            const float z = pts[p*3 + 2] - X.tz;
            const float qx = qcoord(X.m00, X.m01, X.m02, x, y, z);
            const float qy = qcoord(X.m10, X.m11, X.m12, x, y, z);
            const float qz = qcoord(X.m20, X.m21, X.m22, x, y, z);
            const int bn = coarse_key(qy, qz);
            const unsigned r = atomicAdd(&scur[bn], 1u);
            unsigned pos = sbase[bn] + r;
            if (pos >= (unsigned)npts) pos = (unsigned)npts - 1u;  // insurance
            vf4 v; v.x = qx; v.y = qy; v.z = qz; v.w = __int_as_float(p);
            rec[pos] = v;
        }
    }
}

// ---------------------------------------------------------------- pass B ----
// One block per coarse bin: in-LDS, in-place subsort to (y-in-tile, x>>4)
// order -> 256 keys. Order affects only performance, never correctness, so
// an overflowed bin (never expected at ~60 sigma) just skips sorting.
__global__ __launch_bounds__(1024)
void k_subsort(vf4* __restrict__ rec, const unsigned* __restrict__ histA,
               const unsigned* __restrict__ baseA)
{
    const int cbn = blockIdx.x;
    const int t = threadIdx.x;
    const unsigned n = histA[cbn];
    const unsigned b0 = baseA[cbn];
    const int ybase = (cbn & 3) << 5;

    if (n == 0u || n > (unsigned)SUB_CAP) return;

    __shared__ vf4 c[SUB_CAP];
    __shared__ unsigned h[256], cur[256];
    for (int k = t; k < 256; k += 1024) h[k] = 0u;
    __syncthreads();

    for (unsigned i = t; i < n; i += 1024) {
        const vf4 v = rec[b0 + i];
        c[i] = v;
        const int ky = min(max(clamp_idx(v.y) - ybase, 0), 31);
        const int kx = clamp_idx(v.x) >> 4;
        atomicAdd(&h[(ky << 3) | kx], 1u);
    }
    __syncthreads();
    if (t == 0) {
        unsigned run = 0u;
        for (int k = 0; k < 256; ++k) { cur[k] = run; run += h[k]; }
    }
    __syncthreads();
    for (unsigned i = t; i < n; i += 1024) {
        const vf4 v = c[i];
        const int ky = min(max(clamp_idx(v.y) - ybase, 0), 31);
        const int kx = clamp_idx(v.x) >> 4;
        const unsigned pos = atomicAdd(&cur[(ky << 3) | kx], 1u);
        rec[b0 + pos] = v;          // block-exclusive range: no false sharing
    }
}

// ---------------------------------------------------------------- k_main ----
__global__ __launch_bounds__(TPM)
void k_main6(const vf4* __restrict__ rec, const float* __restrict__ cb,
             float* __restrict__ out, int npts, int nwg)
{
    // Bijective XCD swizzle: blocks resident on one XCD process a contiguous
    // span of the sorted stream -> contiguous codebook window in its L2.
    const int bid = blockIdx.x;
    const int q = nwg >> 3, r = nwg & 7;
    const int xcd = bid & 7, lin = bid >> 3;
    const int blk = (xcd < r ? xcd * (q + 1) : r * (q + 1) + (xcd - r) * q) + lin;

    __shared__ vf4 srec[PPB];
    const int t = threadIdx.x;
    const int g0 = blk * PPB;
    if (t < PPB) {
        const int g = g0 + t;
        if (g < npts) srec[t] = __builtin_nontemporal_load(&rec[g]);
    }
    __syncthreads();

    const int pl = t / 9;
    const int f  = t - pl * 9;
    const int p  = g0 + pl;
    if (p >= npts) return;

    const vf4 rr = srec[pl];
    const float qx = rr.x, qy = rr.y, qz = rr.z;
    const int idx = __float_as_int(rr.w);

    const float fx = floorf(qx), fy = floorf(qy), fz = floorf(qz);
    const float wx1 = qx - fx, wy1 = qy - fy, wz1 = qz - fz;
    const float wx0 = 1.0f - wx1, wy0 = 1.0f - wy1, wz0 = 1.0f - wz1;
    const int ix0 = clamp_idx(qx); const int ix1 = min(ix0 + 1, RES - 1);
    const int iy0 = clamp_idx(qy); const int iy1 = min(iy0 + 1, RES - 1);
    const int iz0 = clamp_idx(qz); const int iz1 = min(iz0 + 1, RES - 1);

    int   ro[8];
    float w[8];
    #pragma unroll
    for (int k = 0; k < 8; ++k) {
        const int dx = k & 1, dy = (k >> 1) & 1, dz = k >> 2;
        ro[k] = (dx ? ix1 : ix0) + ((dy ? iy1 : iy0) << 7) + ((dz ? iz1 : iz0) << 14);
        w[k]  = (dx ? wx1 : wx0) * (dy ? wy1 : wy0) * (dz ? wz1 : wz0);
    }

    // Cache-hot gathers: sorted order makes the live window ~9 KB.
    const float* cbf = cb + 2 * f;
    vf2 v[8];
    #pragma unroll
    for (int k = 0; k < 8; ++k)
        v[k] = *reinterpret_cast<const vf2*>(cbf + (size_t)ro[k] * 18);

    float ax = 0.0f, ay = 0.0f;
    #pragma unroll
    for (int k = 0; k < 8; ++k) { ax += v[k].x * w[k]; ay += v[k].y * w[k]; }

    // CACHEABLE scattered store (the R8 change): lands in L2/L3, lines merge
    // both point-halves there and write back full lines asynchronously.
    vf2 o; o.x = ax; o.y = ay;
    *reinterpret_cast<vf2*>(out + (size_t)idx * 18 + 2 * f) = o;
}

// ---------------- R2 fallback (used only if workspace is too small) ----------
__global__ __launch_bounds__(TPM)
void dense_grid_trilerp(const float* __restrict__ pts,
                        const float* __restrict__ cb,
                        const float* __restrict__ tr,
                        float* __restrict__ out,
                        int npts)
{
    __shared__ float spts[PPB * 3];
    if (threadIdx.x < PPB * 3) {
        int g = blockIdx.x * (PPB * 3) + threadIdx.x;
        spts[threadIdx.x] = (g < npts * 3) ? __builtin_nontemporal_load(&pts[g]) : 0.0f;
    }
    __syncthreads();

    const int pl = threadIdx.x / 9;
    const int f  = threadIdx.x - pl * 9;
    const int p  = blockIdx.x * PPB + pl;
    if (p >= npts) return;

    const Xf X = load_xf(tr);
    const float x = spts[pl*3 + 0] - X.tx;
    const float y = spts[pl*3 + 1] - X.ty;
    const float z = spts[pl*3 + 2] - X.tz;
    const float qx = qcoord(X.m00, X.m01, X.m02, x, y, z);
    const float qy = qcoord(X.m10, X.m11, X.m12, x, y, z);
    const float qz = qcoord(X.m20, X.m21, X.m22, x, y, z);

    const float fx = floorf(qx), fy = floorf(qy), fz = floorf(qz);
    const float wx1 = qx - fx, wy1 = qy - fy, wz1 = qz - fz;
    const float wx0 = 1.0f - wx1, wy0 = 1.0f - wy1, wz0 = 1.0f - wz1;
    const int ix0 = clamp_idx(qx); const int ix1 = min(ix0 + 1, RES - 1);
    const int iy0 = clamp_idx(qy); const int iy1 = min(iy0 + 1, RES - 1);
    const int iz0 = clamp_idx(qz); const int iz1 = min(iz0 + 1, RES - 1);

    int   ro[8];
    float w[8];
    #pragma unroll
    for (int k = 0; k < 8; ++k) {
        const int dx = k & 1, dy = (k >> 1) & 1, dz = k >> 2;
        ro[k] = (dx ? ix1 : ix0) + ((dy ? iy1 : iy0) << 7) + ((dz ? iz1 : iz0) << 14);
        w[k]  = (dx ? wx1 : wx0) * (dy ? wy1 : wy0) * (dz ? wz1 : wz0);
    }

    const float* cbf = cb + 2 * f;
    vf2 v[8];
    #pragma unroll
    for (int k = 0; k < 8; ++k)
        v[k] = *reinterpret_cast<const vf2*>(cbf + (size_t)ro[k] * 18);

    float ax = 0.0f, ay = 0.0f;
    #pragma unroll
    for (int k = 0; k < 8; ++k) { ax += v[k].x * w[k]; ay += v[k].y * w[k]; }

    vf2 o; o.x = ax; o.y = ay;
    __builtin_nontemporal_store(o, reinterpret_cast<vf2*>(out + p * 18 + 2 * f));
}

extern "C" void kernel_launch(void* const* d_in, const int* in_sizes, int n_in,
                              void* d_out, int out_size, void* d_ws, size_t ws_size,
                              hipStream_t stream) {
    const float* pts = (const float*)d_in[0];   // [4*524288, 3] f32
    const float* cb  = (const float*)d_in[1];   // [128^3, 18] f32
    const float* tr  = (const float*)d_in[2];   // [4,4] f32
    float* out = (float*)d_out;                 // [4*524288, 18] f32

    const int npts = in_sizes[0] / 3;

    // meta: histA(512) baseA(512) cursorA(512) = 6144 B (256-aligned)
    const size_t meta = (size_t)(NBA * 3) * sizeof(unsigned);
    const size_t need = meta + (size_t)npts * 16;
    if (d_ws == nullptr || ws_size < need || npts <= 0) {
        const int blocks = (npts + PPB - 1) / PPB;
        dense_grid_trilerp<<<blocks, TPM, 0, stream>>>(pts, cb, tr, out, npts);
        return;
    }

    unsigned* histA   = (unsigned*)d_ws;
    unsigned* baseA   = histA + NBA;
    unsigned* cursorA = baseA + NBA;
    vf4* rec = (vf4*)((char*)d_ws + meta);

    const int nwg = (npts + PPB - 1) / PPB;
    hipMemsetAsync(histA, 0, NBA * sizeof(unsigned), stream);
    k_histA<<<(npts + HIST_CHUNK - 1) / HIST_CHUNK, 256, 0, stream>>>(pts, tr, histA, npts);
    k_scanA<<<1, NBA, 0, stream>>>(histA, baseA, cursorA);
    k_scatA<<<(npts + SCAT_CHUNK - 1) / SCAT_CHUNK, 256, 0, stream>>>(pts, tr, cursorA, rec, npts);
    k_subsort<<<NBA, 1024, 0, stream>>>(rec, histA, baseA);
    k_main6<<<nwg, TPM, 0, stream>>>(rec, cb, out, npts, nwg);
}